// Round 3
// baseline (581.880 us; speedup 1.0000x reference)
//
#include <hip/hip_runtime.h>

#define NN 50000
#define NE 800000
#define INF 256
#define HID 256
#define NC 64

typedef short short8 __attribute__((ext_vector_type(8)));
typedef float f32x4 __attribute__((ext_vector_type(4)));

__device__ __forceinline__ unsigned short f2bf(float x) {
    unsigned u = __builtin_bit_cast(unsigned, x);
    u += 0x7FFFu + ((u >> 16) & 1u);          // RNE
    return (unsigned short)(u >> 16);
}
__device__ __forceinline__ float bf2f(unsigned short h) {
    unsigned u = ((unsigned)h) << 16;
    return __builtin_bit_cast(float, u);
}

// ---------- CSR build ----------

__global__ __launch_bounds__(256) void count_kernel(const int* __restrict__ src,
    const int* __restrict__ dst, int* __restrict__ cnt_out, int* __restrict__ cnt_in, int E)
{
    int e = blockIdx.x * 256 + threadIdx.x;
    if (e < E) {
        atomicAdd(&cnt_out[src[e]], 1);
        atomicAdd(&cnt_in[dst[e]], 1);
    }
}

__global__ __launch_bounds__(256) void inv_kernel(const int* __restrict__ cnt_out,
    const int* __restrict__ cnt_in, float* __restrict__ inv_out, float* __restrict__ inv_in, int n)
{
    int i = blockIdx.x * 256 + threadIdx.x;
    if (i < n) {
        inv_out[i] = rsqrtf(fmaxf((float)cnt_out[i], 1.0f));
        inv_in[i]  = rsqrtf(fmaxf((float)cnt_in[i], 1.0f));
    }
}

__global__ __launch_bounds__(1024) void scan_kernel(const int* __restrict__ cnt,
    int* __restrict__ rs, int n)
{
    __shared__ int part[1024];
    int tid = threadIdx.x;
    const int CH = (NN + 1023) / 1024;
    int base = tid * CH;
    int s = 0;
    for (int i = 0; i < CH; ++i) {
        int idx = base + i;
        if (idx < n) s += cnt[idx];
    }
    part[tid] = s;
    __syncthreads();
    for (int off = 1; off < 1024; off <<= 1) {
        int v = (tid >= off) ? part[tid - off] : 0;
        __syncthreads();
        part[tid] += v;
        __syncthreads();
    }
    int run = (tid == 0) ? 0 : part[tid - 1];
    for (int i = 0; i < CH; ++i) {
        int idx = base + i;
        if (idx < n) { rs[idx] = run; run += cnt[idx]; }
    }
}

__global__ __launch_bounds__(256) void fill_kernel(const int* __restrict__ src,
    const int* __restrict__ dst, int* __restrict__ rs, int* __restrict__ csr_src, int E)
{
    int e = blockIdx.x * 256 + threadIdx.x;
    if (e < E) {
        int slot = atomicAdd(&rs[dst[e]], 1);
        csr_src[slot] = src[e];
    }
}

// ---------- W transpose + hi/lo bf16 split (once per launch, tiny) ----------
// W [K][N] fp32 -> WTh/WTl [N][K] bf16 with WTh+WTl ~= W (fp32 split)
__global__ __launch_bounds__(256) void splitW_kernel(const float* __restrict__ W,
    unsigned short* __restrict__ WTh, unsigned short* __restrict__ WTl, int K, int N)
{
    int i = blockIdx.x * 256 + threadIdx.x;
    if (i >= N * K) return;
    int n = i / K, k = i % K;
    float x = W[(size_t)k * N + n];
    unsigned short h = f2bf(x);
    WTh[i] = h;
    WTl[i] = f2bf(x - bf2f(h));
}

// ---------- MFMA GEMM: C_bf16[M,N] = op(A_f32[M,K]) @ B, B given as BT hi/lo [N][K] ----------
// op = relu(x + bias[k]) if RELU_BIAS. 3-pass split: Ah*Bh + Al*Bh + Ah*Bl.
// Block: 256 thr (4 waves), tile 64(M) x 64(N). Wave w owns rows [w*16, w*16+16).
// No LDS: A frags from global fp32 (split in regs), B frags from L2-resident BT.
template<bool RELU_BIAS>
__global__ __launch_bounds__(256) void gemm_mfma_kernel(const float* __restrict__ A,
    const unsigned short* __restrict__ BTh, const unsigned short* __restrict__ BTl,
    unsigned short* __restrict__ C, int M, int N, int K, const float* __restrict__ bias)
{
    int tid = threadIdx.x;
    int w = tid >> 6, lane = tid & 63;
    int r = lane & 15, kg = lane >> 4;
    int rowbase = blockIdx.x * 64;
    int colbase = blockIdx.y * 64;
    int arow = rowbase + w * 16 + r;
    if (arow >= M) arow = M - 1;                 // clamp; stores are guarded
    const float* Arow = A + (size_t)arow * K;

    f32x4 acc[4] = {{0,0,0,0},{0,0,0,0},{0,0,0,0},{0,0,0,0}};

    for (int kb = 0; kb < K; kb += 32) {
        int k0 = kb + kg * 8;
        float4 a0 = *(const float4*)&Arow[k0];
        float4 a1 = *(const float4*)&Arow[k0 + 4];
        float xs[8] = {a0.x, a0.y, a0.z, a0.w, a1.x, a1.y, a1.z, a1.w};
        if (RELU_BIAS) {
            float4 b0 = *(const float4*)&bias[k0];
            float4 b1 = *(const float4*)&bias[k0 + 4];
            float bs[8] = {b0.x, b0.y, b0.z, b0.w, b1.x, b1.y, b1.z, b1.w};
            #pragma unroll
            for (int t = 0; t < 8; ++t) xs[t] = fmaxf(xs[t] + bs[t], 0.0f);
        }
        short8 ah, al;
        #pragma unroll
        for (int t = 0; t < 8; ++t) {
            unsigned short h = f2bf(xs[t]);
            ah[t] = (short)h;
            al[t] = (short)f2bf(xs[t] - bf2f(h));
        }
        #pragma unroll
        for (int ct = 0; ct < 4; ++ct) {
            size_t boff = (size_t)(colbase + ct * 16 + r) * K + k0;
            short8 bh = *(const short8*)&BTh[boff];
            short8 bl = *(const short8*)&BTl[boff];
            acc[ct] = __builtin_amdgcn_mfma_f32_16x16x32_bf16(ah, bh, acc[ct], 0, 0, 0);
            acc[ct] = __builtin_amdgcn_mfma_f32_16x16x32_bf16(al, bh, acc[ct], 0, 0, 0);
            acc[ct] = __builtin_amdgcn_mfma_f32_16x16x32_bf16(ah, bl, acc[ct], 0, 0, 0);
        }
    }
    // D layout: col = lane&15, row = (lane>>4)*4 + reg
    #pragma unroll
    for (int ct = 0; ct < 4; ++ct) {
        #pragma unroll
        for (int reg = 0; reg < 4; ++reg) {
            int orow = rowbase + w * 16 + kg * 4 + reg;
            if (orow < M)
                C[(size_t)orow * N + colbase + ct * 16 + r] = f2bf(acc[ct][reg]);
        }
    }
}

// ---------- CSR gathers (bf16 in, fp32 accumulate) ----------

// One wave per dst node; lane owns 4 bf16 (8B) of the 256-wide row.
__global__ __launch_bounds__(256) void gather256_kernel(const unsigned short* __restrict__ h,
    const int* __restrict__ csr_src, const int* __restrict__ rs,
    const float* __restrict__ inv_out, const float* __restrict__ inv_in,
    float* __restrict__ out, int N)
{
    int n = (int)((blockIdx.x * 256 + threadIdx.x) >> 6);
    int lane = threadIdx.x & 63;
    if (n >= N) return;
    int begin = (n == 0) ? 0 : rs[n - 1];
    int end = rs[n];
    float win = inv_in[n];
    float ax = 0.f, ay = 0.f, az = 0.f, aw = 0.f;
    for (int j = begin; j < end; ++j) {
        int s = csr_src[j];
        float wgt = inv_out[s] * win;
        ushort4 v = *(const ushort4*)&h[(size_t)s * 256 + lane * 4];
        ax = fmaf(bf2f(v.x), wgt, ax);
        ay = fmaf(bf2f(v.y), wgt, ay);
        az = fmaf(bf2f(v.z), wgt, az);
        aw = fmaf(bf2f(v.w), wgt, aw);
    }
    float4 o = {ax, ay, az, aw};
    *(float4*)&out[(size_t)n * 256 + lane * 4] = o;
}

// One wave per dst node; lane owns one bf16 of the 64-wide row. Adds b2.
__global__ __launch_bounds__(256) void gather64_kernel(const unsigned short* __restrict__ h,
    const int* __restrict__ csr_src, const int* __restrict__ rs,
    const float* __restrict__ inv_out, const float* __restrict__ inv_in,
    const float* __restrict__ b2, float* __restrict__ out, int N)
{
    int n = (int)((blockIdx.x * 256 + threadIdx.x) >> 6);
    int lane = threadIdx.x & 63;
    if (n >= N) return;
    int begin = (n == 0) ? 0 : rs[n - 1];
    int end = rs[n];
    float win = inv_in[n];
    float acc = 0.f;
    for (int j = begin; j < end; ++j) {
        int s = csr_src[j];
        float wgt = inv_out[s] * win;
        acc = fmaf(bf2f(h[(size_t)s * 64 + lane]), wgt, acc);
    }
    out[(size_t)n * 64 + lane] = acc + b2[lane];
}

extern "C" void kernel_launch(void* const* d_in, const int* in_sizes, int n_in,
                              void* d_out, int out_size, void* d_ws, size_t ws_size,
                              hipStream_t stream)
{
    const float* features = (const float*)d_in[0];
    const int*   edge_index = (const int*)d_in[1];
    const float* W1 = (const float*)d_in[2];
    const float* b1 = (const float*)d_in[3];
    const float* W2 = (const float*)d_in[4];
    const float* b2 = (const float*)d_in[5];
    float* out = (float*)d_out;
    const int* src = edge_index;
    const int* dst = edge_index + NE;

    char* p = (char*)d_ws;
    int* cnt_out = (int*)p;            p += (size_t)NN * 4;
    int* cnt_in  = (int*)p;            p += (size_t)NN * 4;
    float* inv_out = (float*)p;        p += (size_t)NN * 4;
    float* inv_in  = (float*)p;        p += (size_t)NN * 4;
    int* rs      = (int*)p;            p += (size_t)NN * 4;
    int* csr_src = (int*)p;            p += (size_t)NE * 4;
    unsigned short* W1Th = (unsigned short*)p; p += (size_t)HID * INF * 2;
    unsigned short* W1Tl = (unsigned short*)p; p += (size_t)HID * INF * 2;
    unsigned short* W2Th = (unsigned short*)p; p += (size_t)NC * HID * 2;
    unsigned short* W2Tl = (unsigned short*)p; p += (size_t)NC * HID * 2;
    unsigned short* t1   = (unsigned short*)p; p += (size_t)NN * HID * 2;
    unsigned short* t2   = (unsigned short*)p; p += (size_t)NN * NC * 2;
    float* agg1 = (float*)p;           p += (size_t)NN * HID * 4;

    hipMemsetAsync(cnt_out, 0, 2 * (size_t)NN * sizeof(int), stream);

    count_kernel<<<(NE + 255) / 256, 256, 0, stream>>>(src, dst, cnt_out, cnt_in, NE);
    inv_kernel<<<(NN + 255) / 256, 256, 0, stream>>>(cnt_out, cnt_in, inv_out, inv_in, NN);
    scan_kernel<<<1, 1024, 0, stream>>>(cnt_in, rs, NN);
    fill_kernel<<<(NE + 255) / 256, 256, 0, stream>>>(src, dst, rs, csr_src, NE);

    splitW_kernel<<<(INF * HID + 255) / 256, 256, 0, stream>>>(W1, W1Th, W1Tl, INF, HID);
    splitW_kernel<<<(HID * NC + 255) / 256, 256, 0, stream>>>(W2, W2Th, W2Tl, HID, NC);

    // t1(bf16) = X @ W1   [50000,256]@[256,256]
    gemm_mfma_kernel<false><<<dim3((NN + 63) / 64, HID / 64), 256, 0, stream>>>(
        features, W1Th, W1Tl, t1, NN, HID, INF, nullptr);

    // agg1(fp32)[n] = sum_{e: dst=n} t1[src]*w
    gather256_kernel<<<(NN * 64 + 255) / 256, 256, 0, stream>>>(
        t1, csr_src, rs, inv_out, inv_in, agg1, NN);

    // t2(bf16) = relu(agg1 + b1) @ W2   [50000,256]@[256,64]
    gemm_mfma_kernel<true><<<dim3((NN + 63) / 64, NC / 64), 256, 0, stream>>>(
        agg1, W2Th, W2Tl, t2, NN, NC, HID, b1);

    // out[n] = sum t2[src]*w + b2
    gather64_kernel<<<(NN * 64 + 255) / 256, 256, 0, stream>>>(
        t2, csr_src, rs, inv_out, inv_in, b2, out, NN);
}

// Round 4
// 432.477 us; speedup vs baseline: 1.3455x; 1.3455x over previous
//
#include <hip/hip_runtime.h>

#define NN 50000
#define MPAD 50048          // 391 tiles * 128
#define NE 800000

typedef short short8 __attribute__((ext_vector_type(8)));
typedef float f32x4 __attribute__((ext_vector_type(4)));

__device__ __forceinline__ unsigned short f2bf(float x) {
    unsigned u = __builtin_bit_cast(unsigned, x);
    u += 0x7FFFu + ((u >> 16) & 1u);          // RNE
    return (unsigned short)(u >> 16);
}
__device__ __forceinline__ float bf2f(unsigned short h) {
    unsigned u = ((unsigned)h) << 16;
    return __builtin_bit_cast(float, u);
}
__device__ __forceinline__ void gld16(const void* g, void* l) {
    __builtin_amdgcn_global_load_lds(
        (const __attribute__((address_space(1))) unsigned int*)g,
        (__attribute__((address_space(3))) unsigned int*)l, 16, 0, 0);
}

// ---------- CSR build ----------

__global__ __launch_bounds__(256) void count_kernel(const int* __restrict__ src,
    const int* __restrict__ dst, int* __restrict__ cnt_out, int* __restrict__ cnt_in, int E)
{
    int e = blockIdx.x * 256 + threadIdx.x;
    if (e < E) {
        atomicAdd(&cnt_out[src[e]], 1);
        atomicAdd(&cnt_in[dst[e]], 1);
    }
}

__global__ __launch_bounds__(256) void inv_kernel(const int* __restrict__ cnt_out,
    const int* __restrict__ cnt_in, float* __restrict__ inv_out, float* __restrict__ inv_in, int n)
{
    int i = blockIdx.x * 256 + threadIdx.x;
    if (i < n) {
        inv_out[i] = rsqrtf(fmaxf((float)cnt_out[i], 1.0f));
        inv_in[i]  = rsqrtf(fmaxf((float)cnt_in[i], 1.0f));
    }
}

__global__ __launch_bounds__(1024) void scan_kernel(const int* __restrict__ cnt,
    int* __restrict__ rs, int n)
{
    __shared__ int part[1024];
    int tid = threadIdx.x;
    const int CH = (NN + 1023) / 1024;
    int base = tid * CH;
    int s = 0;
    for (int i = 0; i < CH; ++i) {
        int idx = base + i;
        if (idx < n) s += cnt[idx];
    }
    part[tid] = s;
    __syncthreads();
    for (int off = 1; off < 1024; off <<= 1) {
        int v = (tid >= off) ? part[tid - off] : 0;
        __syncthreads();
        part[tid] += v;
        __syncthreads();
    }
    int run = (tid == 0) ? 0 : part[tid - 1];
    for (int i = 0; i < CH; ++i) {
        int idx = base + i;
        if (idx < n) { rs[idx] = run; run += cnt[idx]; }
    }
}

__global__ __launch_bounds__(256) void fill_kernel(const int* __restrict__ src,
    const int* __restrict__ dst, int* __restrict__ rs, int* __restrict__ csr_src, int E)
{
    int e = blockIdx.x * 256 + threadIdx.x;
    if (e < E) {
        int slot = atomicAdd(&rs[dst[e]], 1);
        csr_src[slot] = src[e];
    }
}

// ---------- X hi/lo split into swizzled LDS-image layout ----------
// Layout contract for A-type arrays [row][256]: row stride 256 elems (512B).
// Within a row: 4 k-blocks of 64 elems (128B); within a k-block, 8 chunks of
// 8 elems (16B); chunk at TRUE position c is STORED at c ^ (row&7).
__global__ __launch_bounds__(256) void splitX_kernel(const float* __restrict__ X,
    unsigned short* __restrict__ Xh, unsigned short* __restrict__ Xl)
{
    int i = blockIdx.x * 256 + threadIdx.x;      // chunk id = r*32 + c
    if (i >= NN * 32) return;
    int r = i >> 5, c = i & 31;
    const float* src = X + (size_t)r * 256 + c * 8;
    float4 a0 = *(const float4*)src;
    float4 a1 = *(const float4*)(src + 4);
    float xs[8] = {a0.x, a0.y, a0.z, a0.w, a1.x, a1.y, a1.z, a1.w};
    short8 hv, lv;
    #pragma unroll
    for (int t = 0; t < 8; ++t) {
        unsigned short h = f2bf(xs[t]);
        hv[t] = (short)h;
        lv[t] = (short)f2bf(xs[t] - bf2f(h));
    }
    size_t off = (size_t)r * 256 + (c >> 3) * 64 + (((c & 7) ^ (r & 7)) * 8);
    *(short8*)&Xh[off] = hv;
    *(short8*)&Xl[off] = lv;
}

// ---------- W transpose+split into [N][512] bf16 (hi | lo), swizzled per col ----------
// W is [256][N] fp32. BT[col][0..255]=hi, [256..511]=lo; same chunk swizzle by col&7.
__global__ __launch_bounds__(256) void splitW_kernel(const float* __restrict__ W,
    unsigned short* __restrict__ BT, int N)
{
    int i = blockIdx.x * 256 + threadIdx.x;      // col*32 + kc
    if (i >= N * 32) return;
    int col = i >> 5, kc = i & 31;
    short8 hv, lv;
    #pragma unroll
    for (int j = 0; j < 8; ++j) {
        float x = W[(size_t)(kc * 8 + j) * N + col];
        unsigned short h = f2bf(x);
        hv[j] = (short)h;
        lv[j] = (short)f2bf(x - bf2f(h));
    }
    size_t base = (size_t)col * 512;
    size_t o = (kc >> 3) * 64 + (((kc & 7) ^ (col & 7)) * 8);
    *(short8*)&BT[base + o] = hv;
    *(short8*)&BT[base + 256 + o] = lv;
}

// ---------- split-bf16 MFMA GEMM ----------
// C[M x Ntot] = (A_hi+A_lo)[M x 256] @ (B_hi+B_lo)[256 x Ntot], 3-term split,
// epilogue scale by inv_out[row]. A given as swizzled images Ah/Al [MPAD][256];
// B as BT [Ntot][512] swizzled. Tile 128 x BN, 4 waves (2M x 2N), BK=64, K'=768.
template<int BN, bool SWZ_OUT>
__global__ __launch_bounds__(256) void gemm_sp_kernel(
    const unsigned short* __restrict__ Ah, const unsigned short* __restrict__ Al,
    const unsigned short* __restrict__ BT, const float* __restrict__ inv_out,
    unsigned short* __restrict__ C, int M, int Ntot)
{
    constexpr int WN = BN / 2;       // wave col span
    constexpr int NF = WN / 16;      // B frags per wave
    constexpr int BI = BN / 32;      // B stage issues per wave
    __shared__ unsigned short As[128 * 64];
    __shared__ unsigned short Bs[BN * 64];
    const int tid = threadIdx.x;
    const int w = tid >> 6, lane = tid & 63;
    const int wm = w >> 1, wn = w & 1;
    const int r = lane & 15, kg = lane >> 4;
    const int rowbase = blockIdx.x * 128;
    const int colbase = blockIdx.y * BN;

    f32x4 acc[4][NF] = {};

    for (int t = 0; t < 12; ++t) {
        const int ph = t >> 2;                    // 0:Ah*Bh 1:Al*Bh 2:Ah*Bl
        const int kb = t & 3;
        const unsigned short* Asrc = (ph == 1) ? Al : Ah;
        const int bsel = (ph == 2) ? 256 : 0;
        #pragma unroll
        for (int i = 0; i < 4; ++i) {             // A tile: 128x64 bf16 = 1024 chunks
            int ct = (w * 4 + i) * 64 + lane;
            int row = ct >> 3, c = ct & 7;
            gld16(Asrc + (size_t)(rowbase + row) * 256 + kb * 64 + c * 8,
                  (unsigned short*)As + (size_t)ct * 8);
        }
        #pragma unroll
        for (int i = 0; i < BI; ++i) {            // B tile: BN x 64 bf16
            int ct = (w * BI + i) * 64 + lane;
            int col = ct >> 3, c = ct & 7;
            gld16(BT + (size_t)(colbase + col) * 512 + bsel + kb * 64 + c * 8,
                  (unsigned short*)Bs + (size_t)ct * 8);
        }
        __syncthreads();
        #pragma unroll
        for (int ks = 0; ks < 2; ++ks) {
            short8 af[4];
            #pragma unroll
            for (int mf = 0; mf < 4; ++mf) {
                int row = wm * 64 + mf * 16 + r;
                af[mf] = *(const short8*)&As[row * 64 + (((ks * 4 + kg) ^ (row & 7)) * 8)];
            }
            #pragma unroll
            for (int nf = 0; nf < NF; ++nf) {
                int col = wn * WN + nf * 16 + r;
                short8 bf = *(const short8*)&Bs[col * 64 + (((ks * 4 + kg) ^ (col & 7)) * 8)];
                #pragma unroll
                for (int mf = 0; mf < 4; ++mf)
                    acc[mf][nf] = __builtin_amdgcn_mfma_f32_16x16x32_bf16(af[mf], bf, acc[mf][nf], 0, 0, 0);
            }
        }
        __syncthreads();
    }

    // D layout: col = lane&15, row = (lane>>4)*4 + reg
    #pragma unroll
    for (int mf = 0; mf < 4; ++mf) {
        #pragma unroll
        for (int reg = 0; reg < 4; ++reg) {
            int orow = rowbase + wm * 64 + mf * 16 + kg * 4 + reg;
            if (orow >= M) continue;
            float sc = inv_out[orow];
            #pragma unroll
            for (int nf = 0; nf < NF; ++nf) {
                int ocol = colbase + wn * WN + nf * 16 + r;
                unsigned short v = f2bf(acc[mf][nf][reg] * sc);
                if (SWZ_OUT) {
                    size_t idx = (size_t)orow * 256 + (ocol >> 6) * 64
                               + ((((ocol >> 3) & 7) ^ (orow & 7)) * 8) + (ocol & 7);
                    C[idx] = v;
                } else {
                    C[(size_t)orow * Ntot + ocol] = v;
                }
            }
        }
    }
}

// ---------- gather 256-wide: pure sum (weights pre-baked), fused bias+relu+split ----------
// One wave per dst node. t1s is swizzled image (row-uniform within a wave).
__global__ __launch_bounds__(256) void gather256_kernel(const unsigned short* __restrict__ t1s,
    const int* __restrict__ csr_src, const int* __restrict__ rs,
    const float* __restrict__ inv_in, const float* __restrict__ b1,
    unsigned short* __restrict__ Ah2, unsigned short* __restrict__ Al2)
{
    int n = (int)((blockIdx.x * 256 + threadIdx.x) >> 6);
    int lane = threadIdx.x & 63;
    if (n >= NN) return;
    int begin = (n == 0) ? 0 : rs[n - 1];
    int end = rs[n];
    int c = lane >> 1, h = lane & 1;             // true chunk c, 8B-half h
    int cc = c & 7;
    int sub = (c >> 3) * 64 + h * 4;
    float a0 = 0.f, a1 = 0.f, a2 = 0.f, a3 = 0.f;
    #pragma unroll 2
    for (int j = begin; j < end; ++j) {
        int s = csr_src[j];
        ushort4 v = *(const ushort4*)&t1s[(size_t)s * 256 + sub + ((cc ^ (s & 7)) * 8)];
        a0 += bf2f(v.x); a1 += bf2f(v.y); a2 += bf2f(v.z); a3 += bf2f(v.w);
    }
    float win = inv_in[n];
    int k0 = c * 8 + h * 4;
    float4 bb = *(const float4*)&b1[k0];
    float x0 = fmaxf(fmaf(a0, win, bb.x), 0.f);
    float x1 = fmaxf(fmaf(a1, win, bb.y), 0.f);
    float x2 = fmaxf(fmaf(a2, win, bb.z), 0.f);
    float x3 = fmaxf(fmaf(a3, win, bb.w), 0.f);
    unsigned short h0 = f2bf(x0), h1 = f2bf(x1), h2 = f2bf(x2), h3 = f2bf(x3);
    ushort4 hv = {h0, h1, h2, h3};
    ushort4 lv = {f2bf(x0 - bf2f(h0)), f2bf(x1 - bf2f(h1)),
                  f2bf(x2 - bf2f(h2)), f2bf(x3 - bf2f(h3))};
    size_t off = (size_t)n * 256 + sub + ((cc ^ (n & 7)) * 8);
    *(ushort4*)&Ah2[off] = hv;
    *(ushort4*)&Al2[off] = lv;
}

// ---------- gather 64-wide: pure sum + inv_in scale + b2 ----------
__global__ __launch_bounds__(256) void gather64_kernel(const unsigned short* __restrict__ t2,
    const int* __restrict__ csr_src, const int* __restrict__ rs,
    const float* __restrict__ inv_in, const float* __restrict__ b2,
    float* __restrict__ out)
{
    int n = (int)((blockIdx.x * 256 + threadIdx.x) >> 6);
    int lane = threadIdx.x & 63;
    if (n >= NN) return;
    int begin = (n == 0) ? 0 : rs[n - 1];
    int end = rs[n];
    float acc = 0.f;
    #pragma unroll 2
    for (int j = begin; j < end; ++j) {
        int s = csr_src[j];
        acc += bf2f(t2[(size_t)s * 64 + lane]);
    }
    out[(size_t)n * 64 + lane] = fmaf(acc, inv_in[n], b2[lane]);
}

extern "C" void kernel_launch(void* const* d_in, const int* in_sizes, int n_in,
                              void* d_out, int out_size, void* d_ws, size_t ws_size,
                              hipStream_t stream)
{
    const float* features = (const float*)d_in[0];
    const int*   edge_index = (const int*)d_in[1];
    const float* W1 = (const float*)d_in[2];
    const float* b1 = (const float*)d_in[3];
    const float* W2 = (const float*)d_in[4];
    const float* b2 = (const float*)d_in[5];
    float* out = (float*)d_out;
    const int* src = edge_index;
    const int* dst = edge_index + NE;

    char* p = (char*)d_ws;
    int* cnt_out = (int*)p;            p += (size_t)NN * 4;
    int* cnt_in  = (int*)p;            p += (size_t)NN * 4;
    float* inv_out = (float*)p;        p += (size_t)NN * 4;
    float* inv_in  = (float*)p;        p += (size_t)NN * 4;
    int* rs      = (int*)p;            p += (size_t)NN * 4;
    int* csr_src = (int*)p;            p += (size_t)NE * 4;
    unsigned short* W1T = (unsigned short*)p;  p += (size_t)256 * 512 * 2;
    unsigned short* W2T = (unsigned short*)p;  p += (size_t)64 * 512 * 2;
    unsigned short* Xh  = (unsigned short*)p;  p += (size_t)MPAD * 256 * 2;
    unsigned short* Xl  = (unsigned short*)p;  p += (size_t)MPAD * 256 * 2;
    unsigned short* t1s = (unsigned short*)p;  p += (size_t)NN * 256 * 2;
    unsigned short* Ah2 = (unsigned short*)p;  p += (size_t)MPAD * 256 * 2;
    unsigned short* Al2 = (unsigned short*)p;  p += (size_t)MPAD * 256 * 2;
    unsigned short* t2  = (unsigned short*)p;  p += (size_t)NN * 64 * 2;

    hipMemsetAsync(cnt_out, 0, 2 * (size_t)NN * sizeof(int), stream);

    count_kernel<<<(NE + 255) / 256, 256, 0, stream>>>(src, dst, cnt_out, cnt_in, NE);
    inv_kernel<<<(NN + 255) / 256, 256, 0, stream>>>(cnt_out, cnt_in, inv_out, inv_in, NN);
    scan_kernel<<<1, 1024, 0, stream>>>(cnt_in, rs, NN);
    fill_kernel<<<(NE + 255) / 256, 256, 0, stream>>>(src, dst, rs, csr_src, NE);

    splitX_kernel<<<(NN * 32 + 255) / 256, 256, 0, stream>>>(features, Xh, Xl);
    splitW_kernel<<<(256 * 32 + 255) / 256, 256, 0, stream>>>(W1, W1T, 256);
    splitW_kernel<<<(64 * 32 + 255) / 256, 256, 0, stream>>>(W2, W2T, 64);

    // t1s(bf16, swz) = (X @ W1) * inv_out[row]
    gemm_sp_kernel<128, true><<<dim3(MPAD / 128, 2), 256, 0, stream>>>(
        Xh, Xl, W1T, inv_out, t1s, NN, 256);

    // Ah2/Al2 = split(relu(sum_{e:dst=n} t1s[src] * inv_in[n] + b1))
    gather256_kernel<<<(NN * 64 + 255) / 256, 256, 0, stream>>>(
        t1s, csr_src, rs, inv_in, b1, Ah2, Al2);

    // t2(bf16, linear) = (h2 @ W2) * inv_out[row]
    gemm_sp_kernel<64, false><<<dim3(MPAD / 128, 1), 256, 0, stream>>>(
        Ah2, Al2, W2T, inv_out, t2, NN, 64);

    // out = sum t2[src] * inv_in[n] + b2
    gather64_kernel<<<(NN * 64 + 255) / 256, 256, 0, stream>>>(
        t2, csr_src, rs, inv_in, b2, out);
}

// Round 5
// 343.007 us; speedup vs baseline: 1.6964x; 1.2608x over previous
//
#include <hip/hip_runtime.h>

#define NN 50000
#define MPAD 50048          // 391 tiles * 128
#define NE 800000
#define SCAN_BLOCKS 49      // ceil(50000 / 1024)

typedef short short8 __attribute__((ext_vector_type(8)));
typedef float f32x4 __attribute__((ext_vector_type(4)));

__device__ __forceinline__ unsigned short f2bf(float x) {
    unsigned u = __builtin_bit_cast(unsigned, x);
    u += 0x7FFFu + ((u >> 16) & 1u);          // RNE
    return (unsigned short)(u >> 16);
}
__device__ __forceinline__ float bf2f(unsigned short h) {
    unsigned u = ((unsigned)h) << 16;
    return __builtin_bit_cast(float, u);
}
__device__ __forceinline__ void gld16(const void* g, void* l) {
    __builtin_amdgcn_global_load_lds(
        (const __attribute__((address_space(1))) unsigned int*)g,
        (__attribute__((address_space(3))) unsigned int*)l, 16, 0, 0);
}

// ---------- CSR build ----------

__global__ __launch_bounds__(256) void count_kernel(const int* __restrict__ src,
    const int* __restrict__ dst, int* __restrict__ cnt_out, int* __restrict__ cnt_in, int E)
{
    int e = blockIdx.x * 256 + threadIdx.x;
    if (e < E) {
        atomicAdd(&cnt_out[src[e]], 1);
        atomicAdd(&cnt_in[dst[e]], 1);
    }
}

__global__ __launch_bounds__(256) void inv_kernel(const int* __restrict__ cnt_out,
    const int* __restrict__ cnt_in, float* __restrict__ inv_out, float* __restrict__ inv_in, int n)
{
    int i = blockIdx.x * 256 + threadIdx.x;
    if (i < n) {
        inv_out[i] = rsqrtf(fmaxf((float)cnt_out[i], 1.0f));
        inv_in[i]  = rsqrtf(fmaxf((float)cnt_in[i], 1.0f));
    }
}

// --- hierarchical exclusive scan of cnt_in[0..NN) -> rs[0..NN) ---
// A: per-block (1024 elems) sums
__global__ __launch_bounds__(256) void scanA_kernel(const int* __restrict__ cnt,
    int* __restrict__ bsum)
{
    __shared__ int sm[256];
    int b = blockIdx.x, tid = threadIdx.x;
    int base = b * 1024 + tid * 4;
    int s = 0;
    #pragma unroll
    for (int i = 0; i < 4; ++i) {
        int idx = base + i;
        if (idx < NN) s += cnt[idx];
    }
    sm[tid] = s;
    __syncthreads();
    for (int off = 128; off > 0; off >>= 1) {
        if (tid < off) sm[tid] += sm[tid + off];
        __syncthreads();
    }
    if (tid == 0) bsum[b] = sm[0];
}

// B: one-wave exclusive scan of the SCAN_BLOCKS block sums
__global__ __launch_bounds__(64) void scanB_kernel(const int* __restrict__ bsum,
    int* __restrict__ bexcl)
{
    int tid = threadIdx.x;
    int orig = (tid < SCAN_BLOCKS) ? bsum[tid] : 0;
    int v = orig;
    #pragma unroll
    for (int off = 1; off < 64; off <<= 1) {
        int u = __shfl_up(v, off, 64);
        if (tid >= off) v += u;
    }
    if (tid < SCAN_BLOCKS) bexcl[tid] = v - orig;
}

// C: per-block exclusive scan + block offset -> rs
__global__ __launch_bounds__(256) void scanC_kernel(const int* __restrict__ cnt,
    const int* __restrict__ bexcl, int* __restrict__ rs)
{
    __shared__ int wsum[4];
    int b = blockIdx.x, tid = threadIdx.x;
    int lane = tid & 63, wv = tid >> 6;
    int base = b * 1024 + tid * 4;
    int v[4]; int s = 0;
    #pragma unroll
    for (int i = 0; i < 4; ++i) {
        int idx = base + i;
        v[i] = (idx < NN) ? cnt[idx] : 0;
        s += v[i];
    }
    int inc = s;
    #pragma unroll
    for (int off = 1; off < 64; off <<= 1) {
        int u = __shfl_up(inc, off, 64);
        if (lane >= off) inc += u;
    }
    if (lane == 63) wsum[wv] = inc;
    __syncthreads();
    int wo = 0;
    for (int i = 0; i < wv; ++i) wo += wsum[i];
    int run = wo + (inc - s) + bexcl[b];
    #pragma unroll
    for (int i = 0; i < 4; ++i) {
        int idx = base + i;
        if (idx < NN) { rs[idx] = run; run += v[i]; }
    }
}

__global__ __launch_bounds__(256) void fill_kernel(const int* __restrict__ src,
    const int* __restrict__ dst, int* __restrict__ rs, int* __restrict__ csr_src, int E)
{
    int e = blockIdx.x * 256 + threadIdx.x;
    if (e < E) {
        int slot = atomicAdd(&rs[dst[e]], 1);
        csr_src[slot] = src[e];
    }
}

// ---------- X hi/lo split into swizzled LDS-image layout ----------
// Layout contract for A-type arrays [row][256]: row stride 256 elems (512B).
// Within a row: 4 k-blocks of 64 elems (128B); within a k-block, 8 chunks of
// 8 elems (16B); chunk at TRUE position c is STORED at c ^ (row&7).
__global__ __launch_bounds__(256) void splitX_kernel(const float* __restrict__ X,
    unsigned short* __restrict__ Xh, unsigned short* __restrict__ Xl)
{
    int i = blockIdx.x * 256 + threadIdx.x;      // chunk id = r*32 + c
    if (i >= NN * 32) return;
    int r = i >> 5, c = i & 31;
    const float* src = X + (size_t)r * 256 + c * 8;
    float4 a0 = *(const float4*)src;
    float4 a1 = *(const float4*)(src + 4);
    float xs[8] = {a0.x, a0.y, a0.z, a0.w, a1.x, a1.y, a1.z, a1.w};
    short8 hv, lv;
    #pragma unroll
    for (int t = 0; t < 8; ++t) {
        unsigned short h = f2bf(xs[t]);
        hv[t] = (short)h;
        lv[t] = (short)f2bf(xs[t] - bf2f(h));
    }
    size_t off = (size_t)r * 256 + (c >> 3) * 64 + (((c & 7) ^ (r & 7)) * 8);
    *(short8*)&Xh[off] = hv;
    *(short8*)&Xl[off] = lv;
}

// ---------- W transpose+split into [N][512] bf16 (hi | lo), swizzled per col ----------
__global__ __launch_bounds__(256) void splitW_kernel(const float* __restrict__ W,
    unsigned short* __restrict__ BT, int N)
{
    int i = blockIdx.x * 256 + threadIdx.x;      // col*32 + kc
    if (i >= N * 32) return;
    int col = i >> 5, kc = i & 31;
    short8 hv, lv;
    #pragma unroll
    for (int j = 0; j < 8; ++j) {
        float x = W[(size_t)(kc * 8 + j) * N + col];
        unsigned short h = f2bf(x);
        hv[j] = (short)h;
        lv[j] = (short)f2bf(x - bf2f(h));
    }
    size_t base = (size_t)col * 512;
    size_t o = (kc >> 3) * 64 + (((kc & 7) ^ (col & 7)) * 8);
    *(short8*)&BT[base + o] = hv;
    *(short8*)&BT[base + 256 + o] = lv;
}

// ---------- split-bf16 MFMA GEMM ----------
// C[M x Ntot] = (A_hi+A_lo)[M x 256] @ (B_hi+B_lo)[256 x Ntot], 3-term split,
// epilogue scale by inv_out[row]. Tile 128 x BN, 4 waves (2M x 2N), BK=64.
template<int BN, bool SWZ_OUT>
__global__ __launch_bounds__(256) void gemm_sp_kernel(
    const unsigned short* __restrict__ Ah, const unsigned short* __restrict__ Al,
    const unsigned short* __restrict__ BT, const float* __restrict__ inv_out,
    unsigned short* __restrict__ C, int M, int Ntot)
{
    constexpr int WN = BN / 2;       // wave col span
    constexpr int NF = WN / 16;      // B frags per wave
    constexpr int BI = BN / 32;      // B stage issues per wave
    __shared__ unsigned short As[128 * 64];
    __shared__ unsigned short Bs[BN * 64];
    const int tid = threadIdx.x;
    const int w = tid >> 6, lane = tid & 63;
    const int wm = w >> 1, wn = w & 1;
    const int r = lane & 15, kg = lane >> 4;
    const int rowbase = blockIdx.x * 128;
    const int colbase = blockIdx.y * BN;

    f32x4 acc[4][NF] = {};

    for (int t = 0; t < 12; ++t) {
        const int ph = t >> 2;                    // 0:Ah*Bh 1:Al*Bh 2:Ah*Bl
        const int kb = t & 3;
        const unsigned short* Asrc = (ph == 1) ? Al : Ah;
        const int bsel = (ph == 2) ? 256 : 0;
        #pragma unroll
        for (int i = 0; i < 4; ++i) {             // A tile: 128x64 bf16 = 1024 chunks
            int ct = (w * 4 + i) * 64 + lane;
            int row = ct >> 3, c = ct & 7;
            gld16(Asrc + (size_t)(rowbase + row) * 256 + kb * 64 + c * 8,
                  (unsigned short*)As + (size_t)ct * 8);
        }
        #pragma unroll
        for (int i = 0; i < BI; ++i) {            // B tile: BN x 64 bf16
            int ct = (w * BI + i) * 64 + lane;
            int col = ct >> 3, c = ct & 7;
            gld16(BT + (size_t)(colbase + col) * 512 + bsel + kb * 64 + c * 8,
                  (unsigned short*)Bs + (size_t)ct * 8);
        }
        __syncthreads();
        #pragma unroll
        for (int ks = 0; ks < 2; ++ks) {
            short8 af[4];
            #pragma unroll
            for (int mf = 0; mf < 4; ++mf) {
                int row = wm * 64 + mf * 16 + r;
                af[mf] = *(const short8*)&As[row * 64 + (((ks * 4 + kg) ^ (row & 7)) * 8)];
            }
            #pragma unroll
            for (int nf = 0; nf < NF; ++nf) {
                int col = wn * WN + nf * 16 + r;
                short8 bf = *(const short8*)&Bs[col * 64 + (((ks * 4 + kg) ^ (col & 7)) * 8)];
                #pragma unroll
                for (int mf = 0; mf < 4; ++mf)
                    acc[mf][nf] = __builtin_amdgcn_mfma_f32_16x16x32_bf16(af[mf], bf, acc[mf][nf], 0, 0, 0);
            }
        }
        __syncthreads();
    }

    // D layout: col = lane&15, row = (lane>>4)*4 + reg
    #pragma unroll
    for (int mf = 0; mf < 4; ++mf) {
        #pragma unroll
        for (int reg = 0; reg < 4; ++reg) {
            int orow = rowbase + wm * 64 + mf * 16 + kg * 4 + reg;
            if (orow >= M) continue;
            float sc = inv_out[orow];
            #pragma unroll
            for (int nf = 0; nf < NF; ++nf) {
                int ocol = colbase + wn * WN + nf * 16 + r;
                unsigned short v = f2bf(acc[mf][nf][reg] * sc);
                if (SWZ_OUT) {
                    size_t idx = (size_t)orow * 256 + (ocol >> 6) * 64
                               + ((((ocol >> 3) & 7) ^ (orow & 7)) * 8) + (ocol & 7);
                    C[idx] = v;
                } else {
                    C[(size_t)orow * Ntot + ocol] = v;
                }
            }
        }
    }
}

// ---------- gather 256-wide: pure sum, fused bias+relu+split ----------
__global__ __launch_bounds__(256) void gather256_kernel(const unsigned short* __restrict__ t1s,
    const int* __restrict__ csr_src, const int* __restrict__ rs,
    const float* __restrict__ inv_in, const float* __restrict__ b1,
    unsigned short* __restrict__ Ah2, unsigned short* __restrict__ Al2)
{
    int n = (int)((blockIdx.x * 256 + threadIdx.x) >> 6);
    int lane = threadIdx.x & 63;
    if (n >= NN) return;
    int begin = (n == 0) ? 0 : rs[n - 1];
    int end = rs[n];
    int c = lane >> 1, h = lane & 1;             // true chunk c, 8B-half h
    int cc = c & 7;
    int sub = (c >> 3) * 64 + h * 4;
    float a0 = 0.f, a1 = 0.f, a2 = 0.f, a3 = 0.f;
    #pragma unroll 2
    for (int j = begin; j < end; ++j) {
        int s = csr_src[j];
        ushort4 v = *(const ushort4*)&t1s[(size_t)s * 256 + sub + ((cc ^ (s & 7)) * 8)];
        a0 += bf2f(v.x); a1 += bf2f(v.y); a2 += bf2f(v.z); a3 += bf2f(v.w);
    }
    float win = inv_in[n];
    int k0 = c * 8 + h * 4;
    float4 bb = *(const float4*)&b1[k0];
    float x0 = fmaxf(fmaf(a0, win, bb.x), 0.f);
    float x1 = fmaxf(fmaf(a1, win, bb.y), 0.f);
    float x2 = fmaxf(fmaf(a2, win, bb.z), 0.f);
    float x3 = fmaxf(fmaf(a3, win, bb.w), 0.f);
    unsigned short h0 = f2bf(x0), h1 = f2bf(x1), h2 = f2bf(x2), h3 = f2bf(x3);
    ushort4 hv = {h0, h1, h2, h3};
    ushort4 lv = {f2bf(x0 - bf2f(h0)), f2bf(x1 - bf2f(h1)),
                  f2bf(x2 - bf2f(h2)), f2bf(x3 - bf2f(h3))};
    size_t off = (size_t)n * 256 + sub + ((cc ^ (n & 7)) * 8);
    *(ushort4*)&Ah2[off] = hv;
    *(ushort4*)&Al2[off] = lv;
}

// ---------- gather 64-wide: pure sum + inv_in scale + b2 ----------
__global__ __launch_bounds__(256) void gather64_kernel(const unsigned short* __restrict__ t2,
    const int* __restrict__ csr_src, const int* __restrict__ rs,
    const float* __restrict__ inv_in, const float* __restrict__ b2,
    float* __restrict__ out)
{
    int n = (int)((blockIdx.x * 256 + threadIdx.x) >> 6);
    int lane = threadIdx.x & 63;
    if (n >= NN) return;
    int begin = (n == 0) ? 0 : rs[n - 1];
    int end = rs[n];
    float acc = 0.f;
    #pragma unroll 2
    for (int j = begin; j < end; ++j) {
        int s = csr_src[j];
        acc += bf2f(t2[(size_t)s * 64 + lane]);
    }
    out[(size_t)n * 64 + lane] = fmaf(acc, inv_in[n], b2[lane]);
}

extern "C" void kernel_launch(void* const* d_in, const int* in_sizes, int n_in,
                              void* d_out, int out_size, void* d_ws, size_t ws_size,
                              hipStream_t stream)
{
    const float* features = (const float*)d_in[0];
    const int*   edge_index = (const int*)d_in[1];
    const float* W1 = (const float*)d_in[2];
    const float* b1 = (const float*)d_in[3];
    const float* W2 = (const float*)d_in[4];
    const float* b2 = (const float*)d_in[5];
    float* out = (float*)d_out;
    const int* src = edge_index;
    const int* dst = edge_index + NE;

    char* p = (char*)d_ws;
    int* cnt_out = (int*)p;            p += (size_t)NN * 4;
    int* cnt_in  = (int*)p;            p += (size_t)NN * 4;
    float* inv_out = (float*)p;        p += (size_t)NN * 4;
    float* inv_in  = (float*)p;        p += (size_t)NN * 4;
    int* rs      = (int*)p;            p += (size_t)NN * 4;
    int* csr_src = (int*)p;            p += (size_t)NE * 4;
    int* bsum    = (int*)p;            p += 64 * 4;
    int* bexcl   = (int*)p;            p += 64 * 4;
    unsigned short* W1T = (unsigned short*)p;  p += (size_t)256 * 512 * 2;
    unsigned short* W2T = (unsigned short*)p;  p += (size_t)64 * 512 * 2;
    unsigned short* Xh  = (unsigned short*)p;  p += (size_t)MPAD * 256 * 2;
    unsigned short* Xl  = (unsigned short*)p;  p += (size_t)MPAD * 256 * 2;
    unsigned short* t1s = (unsigned short*)p;  p += (size_t)NN * 256 * 2;
    unsigned short* Ah2 = (unsigned short*)p;  p += (size_t)MPAD * 256 * 2;
    unsigned short* Al2 = (unsigned short*)p;  p += (size_t)MPAD * 256 * 2;
    unsigned short* t2  = (unsigned short*)p;  p += (size_t)NN * 64 * 2;

    hipMemsetAsync(cnt_out, 0, 2 * (size_t)NN * sizeof(int), stream);

    count_kernel<<<(NE + 255) / 256, 256, 0, stream>>>(src, dst, cnt_out, cnt_in, NE);
    inv_kernel<<<(NN + 255) / 256, 256, 0, stream>>>(cnt_out, cnt_in, inv_out, inv_in, NN);
    scanA_kernel<<<SCAN_BLOCKS, 256, 0, stream>>>(cnt_in, bsum);
    scanB_kernel<<<1, 64, 0, stream>>>(bsum, bexcl);
    scanC_kernel<<<SCAN_BLOCKS, 256, 0, stream>>>(cnt_in, bexcl, rs);
    fill_kernel<<<(NE + 255) / 256, 256, 0, stream>>>(src, dst, rs, csr_src, NE);

    splitX_kernel<<<(NN * 32 + 255) / 256, 256, 0, stream>>>(features, Xh, Xl);
    splitW_kernel<<<(256 * 32 + 255) / 256, 256, 0, stream>>>(W1, W1T, 256);
    splitW_kernel<<<(64 * 32 + 255) / 256, 256, 0, stream>>>(W2, W2T, 64);

    // t1s(bf16, swz) = (X @ W1) * inv_out[row]
    gemm_sp_kernel<128, true><<<dim3(MPAD / 128, 2), 256, 0, stream>>>(
        Xh, Xl, W1T, inv_out, t1s, NN, 256);

    // Ah2/Al2 = split(relu(sum_{e:dst=n} t1s[src] * inv_in[n] + b1))
    gather256_kernel<<<(NN * 64 + 255) / 256, 256, 0, stream>>>(
        t1s, csr_src, rs, inv_in, b1, Ah2, Al2);

    // t2(bf16, linear) = (h2 @ W2) * inv_out[row]
    gemm_sp_kernel<64, false><<<dim3(MPAD / 128, 1), 256, 0, stream>>>(
        Ah2, Al2, W2T, inv_out, t2, NN, 64);

    // out = sum t2[src] * inv_in[n] + b2
    gather64_kernel<<<(NN * 64 + 255) / 256, 256, 0, stream>>>(
        t2, csr_src, rs, inv_in, b2, out);
}

// Round 6
// 320.562 us; speedup vs baseline: 1.8152x; 1.0700x over previous
//
#include <hip/hip_runtime.h>

#define NN 50000
#define MPAD 50048          // 391 tiles * 128
#define NE 800000
#define SCAN_BLOCKS 49      // ceil(50000 / 1024)

typedef short short8 __attribute__((ext_vector_type(8)));
typedef float f32x4 __attribute__((ext_vector_type(4)));

__device__ __forceinline__ unsigned short f2bf(float x) {
    unsigned u = __builtin_bit_cast(unsigned, x);
    u += 0x7FFFu + ((u >> 16) & 1u);          // RNE
    return (unsigned short)(u >> 16);
}
__device__ __forceinline__ float bf2f(unsigned short h) {
    unsigned u = ((unsigned)h) << 16;
    return __builtin_bit_cast(float, u);
}
__device__ __forceinline__ void gld16(const void* g, void* l) {
    __builtin_amdgcn_global_load_lds(
        (const __attribute__((address_space(1))) unsigned int*)g,
        (__attribute__((address_space(3))) unsigned int*)l, 16, 0, 0);
}

// ---------- CSR build ----------

__global__ __launch_bounds__(256) void count_kernel(const int* __restrict__ src,
    const int* __restrict__ dst, int* __restrict__ cnt_out, int* __restrict__ cnt_in, int E)
{
    int e = blockIdx.x * 256 + threadIdx.x;
    if (e < E) {
        atomicAdd(&cnt_out[src[e]], 1);
        atomicAdd(&cnt_in[dst[e]], 1);
    }
}

__global__ __launch_bounds__(256) void inv_kernel(const int* __restrict__ cnt_out,
    const int* __restrict__ cnt_in, float* __restrict__ inv_out, float* __restrict__ inv_in, int n)
{
    int i = blockIdx.x * 256 + threadIdx.x;
    if (i < n) {
        inv_out[i] = rsqrtf(fmaxf((float)cnt_out[i], 1.0f));
        inv_in[i]  = rsqrtf(fmaxf((float)cnt_in[i], 1.0f));
    }
}

// --- hierarchical exclusive scan of cnt_in[0..NN) -> rs[0..NN) ---
__global__ __launch_bounds__(256) void scanA_kernel(const int* __restrict__ cnt,
    int* __restrict__ bsum)
{
    __shared__ int sm[256];
    int b = blockIdx.x, tid = threadIdx.x;
    int base = b * 1024 + tid * 4;
    int s = 0;
    #pragma unroll
    for (int i = 0; i < 4; ++i) {
        int idx = base + i;
        if (idx < NN) s += cnt[idx];
    }
    sm[tid] = s;
    __syncthreads();
    for (int off = 128; off > 0; off >>= 1) {
        if (tid < off) sm[tid] += sm[tid + off];
        __syncthreads();
    }
    if (tid == 0) bsum[b] = sm[0];
}

__global__ __launch_bounds__(64) void scanB_kernel(const int* __restrict__ bsum,
    int* __restrict__ bexcl)
{
    int tid = threadIdx.x;
    int orig = (tid < SCAN_BLOCKS) ? bsum[tid] : 0;
    int v = orig;
    #pragma unroll
    for (int off = 1; off < 64; off <<= 1) {
        int u = __shfl_up(v, off, 64);
        if (tid >= off) v += u;
    }
    if (tid < SCAN_BLOCKS) bexcl[tid] = v - orig;
}

__global__ __launch_bounds__(256) void scanC_kernel(const int* __restrict__ cnt,
    const int* __restrict__ bexcl, int* __restrict__ rs)
{
    __shared__ int wsum[4];
    int b = blockIdx.x, tid = threadIdx.x;
    int lane = tid & 63, wv = tid >> 6;
    int base = b * 1024 + tid * 4;
    int v[4]; int s = 0;
    #pragma unroll
    for (int i = 0; i < 4; ++i) {
        int idx = base + i;
        v[i] = (idx < NN) ? cnt[idx] : 0;
        s += v[i];
    }
    int inc = s;
    #pragma unroll
    for (int off = 1; off < 64; off <<= 1) {
        int u = __shfl_up(inc, off, 64);
        if (lane >= off) inc += u;
    }
    if (lane == 63) wsum[wv] = inc;
    __syncthreads();
    int wo = 0;
    for (int i = 0; i < wv; ++i) wo += wsum[i];
    int run = wo + (inc - s) + bexcl[b];
    #pragma unroll
    for (int i = 0; i < 4; ++i) {
        int idx = base + i;
        if (idx < NN) { rs[idx] = run; run += v[i]; }
    }
}

__global__ __launch_bounds__(256) void fill_kernel(const int* __restrict__ src,
    const int* __restrict__ dst, int* __restrict__ rs, int* __restrict__ csr_src, int E)
{
    int e = blockIdx.x * 256 + threadIdx.x;
    if (e < E) {
        int slot = atomicAdd(&rs[dst[e]], 1);
        csr_src[slot] = src[e];
    }
}

// ---------- X hi/lo split into swizzled LDS-image layout ----------
// [row][256]: 4 k-blocks of 64; within k-block, 8 chunks of 8 elems (16B);
// chunk at TRUE position c is STORED at c ^ (row&7).
__global__ __launch_bounds__(256) void splitX_kernel(const float* __restrict__ X,
    unsigned short* __restrict__ Xh, unsigned short* __restrict__ Xl)
{
    int i = blockIdx.x * 256 + threadIdx.x;      // chunk id = r*32 + c
    if (i >= NN * 32) return;
    int r = i >> 5, c = i & 31;
    const float* src = X + (size_t)r * 256 + c * 8;
    float4 a0 = *(const float4*)src;
    float4 a1 = *(const float4*)(src + 4);
    float xs[8] = {a0.x, a0.y, a0.z, a0.w, a1.x, a1.y, a1.z, a1.w};
    short8 hv, lv;
    #pragma unroll
    for (int t = 0; t < 8; ++t) {
        unsigned short h = f2bf(xs[t]);
        hv[t] = (short)h;
        lv[t] = (short)f2bf(xs[t] - bf2f(h));
    }
    size_t off = (size_t)r * 256 + (c >> 3) * 64 + (((c & 7) ^ (r & 7)) * 8);
    *(short8*)&Xh[off] = hv;
    *(short8*)&Xl[off] = lv;
}

// ---------- W transpose+split into [N][512] bf16 (hi | lo), swizzled per col ----------
__global__ __launch_bounds__(256) void splitW_kernel(const float* __restrict__ W,
    unsigned short* __restrict__ BT, int N)
{
    int i = blockIdx.x * 256 + threadIdx.x;      // col*32 + kc
    if (i >= N * 32) return;
    int col = i >> 5, kc = i & 31;
    short8 hv, lv;
    #pragma unroll
    for (int j = 0; j < 8; ++j) {
        float x = W[(size_t)(kc * 8 + j) * N + col];
        unsigned short h = f2bf(x);
        hv[j] = (short)h;
        lv[j] = (short)f2bf(x - bf2f(h));
    }
    size_t base = (size_t)col * 512;
    size_t o = (kc >> 3) * 64 + (((kc & 7) ^ (col & 7)) * 8);
    *(short8*)&BT[base + o] = hv;
    *(short8*)&BT[base + 256 + o] = lv;
}

// ---------- split-bf16 MFMA GEMM, kb-major: stage Ah/Al/Bh/Bl once per kb ----------
// C = (Ah+Al)[Mx256] @ (Bh+Bl)[256xNtot] (3-term), epilogue scale inv_out[row].
// Tile 128 x BN, 4 waves (2M x 2N), BK=64, 4 kb steps.
template<int BN, bool SWZ_OUT>
__global__ __launch_bounds__(256) void gemm_sp_kernel(
    const unsigned short* __restrict__ Ah, const unsigned short* __restrict__ Al,
    const unsigned short* __restrict__ BT, const float* __restrict__ inv_out,
    unsigned short* __restrict__ C, int M, int Ntot)
{
    constexpr int WN = BN / 2;       // wave col span
    constexpr int NF = WN / 16;      // B frags per wave
    constexpr int BI = BN / 32;      // B stage issues per wave
    __shared__ unsigned short Ash[128 * 64];
    __shared__ unsigned short Asl[128 * 64];
    __shared__ unsigned short Bsh[BN * 64];
    __shared__ unsigned short Bsl[BN * 64];
    const int tid = threadIdx.x;
    const int w = tid >> 6, lane = tid & 63;
    const int wm = w >> 1, wn = w & 1;
    const int r = lane & 15, kg = lane >> 4;
    const int rowbase = blockIdx.x * 128;
    const int colbase = blockIdx.y * BN;

    f32x4 acc[4][NF] = {};

    for (int kb = 0; kb < 4; ++kb) {
        #pragma unroll
        for (int i = 0; i < 4; ++i) {             // A tiles: 128x64 bf16 each
            int ct = (w * 4 + i) * 64 + lane;
            int row = ct >> 3, c = ct & 7;
            size_t goff = (size_t)(rowbase + row) * 256 + kb * 64 + c * 8;
            gld16(Ah + goff, (unsigned short*)Ash + (size_t)ct * 8);
            gld16(Al + goff, (unsigned short*)Asl + (size_t)ct * 8);
        }
        #pragma unroll
        for (int i = 0; i < BI; ++i) {            // B tiles: BN x 64 bf16 each
            int ct = (w * BI + i) * 64 + lane;
            int col = ct >> 3, c = ct & 7;
            size_t goff = (size_t)(colbase + col) * 512 + kb * 64 + c * 8;
            gld16(BT + goff, (unsigned short*)Bsh + (size_t)ct * 8);
            gld16(BT + goff + 256, (unsigned short*)Bsl + (size_t)ct * 8);
        }
        __syncthreads();
        #pragma unroll
        for (int ks = 0; ks < 2; ++ks) {
            short8 ahf[4], alf[4];
            #pragma unroll
            for (int mf = 0; mf < 4; ++mf) {
                int row = wm * 64 + mf * 16 + r;
                int lo = row * 64 + (((ks * 4 + kg) ^ (row & 7)) * 8);
                ahf[mf] = *(const short8*)&Ash[lo];
                alf[mf] = *(const short8*)&Asl[lo];
            }
            #pragma unroll
            for (int nf = 0; nf < NF; ++nf) {
                int col = wn * WN + nf * 16 + r;
                int lo = col * 64 + (((ks * 4 + kg) ^ (col & 7)) * 8);
                short8 bh = *(const short8*)&Bsh[lo];
                short8 bl = *(const short8*)&Bsl[lo];
                #pragma unroll
                for (int mf = 0; mf < 4; ++mf) {
                    acc[mf][nf] = __builtin_amdgcn_mfma_f32_16x16x32_bf16(ahf[mf], bh, acc[mf][nf], 0, 0, 0);
                    acc[mf][nf] = __builtin_amdgcn_mfma_f32_16x16x32_bf16(alf[mf], bh, acc[mf][nf], 0, 0, 0);
                    acc[mf][nf] = __builtin_amdgcn_mfma_f32_16x16x32_bf16(ahf[mf], bl, acc[mf][nf], 0, 0, 0);
                }
            }
        }
        __syncthreads();
    }

    // D layout: col = lane&15, row = (lane>>4)*4 + reg
    #pragma unroll
    for (int mf = 0; mf < 4; ++mf) {
        #pragma unroll
        for (int reg = 0; reg < 4; ++reg) {
            int orow = rowbase + wm * 64 + mf * 16 + kg * 4 + reg;
            if (orow >= M) continue;
            float sc = inv_out[orow];
            #pragma unroll
            for (int nf = 0; nf < NF; ++nf) {
                int ocol = colbase + wn * WN + nf * 16 + r;
                unsigned short v = f2bf(acc[mf][nf][reg] * sc);
                if (SWZ_OUT) {
                    size_t idx = (size_t)orow * 256 + (ocol >> 6) * 64
                               + ((((ocol >> 3) & 7) ^ (orow & 7)) * 8) + (ocol & 7);
                    C[idx] = v;
                } else {
                    C[(size_t)orow * Ntot + ocol] = v;
                }
            }
        }
    }
}

// ---------- gather 256-wide: pure sum, unroll-4 pipeline, fused bias+relu+split ----------
__global__ __launch_bounds__(256) void gather256_kernel(const unsigned short* __restrict__ t1s,
    const int* __restrict__ csr_src, const int* __restrict__ rs,
    const float* __restrict__ inv_in, const float* __restrict__ b1,
    unsigned short* __restrict__ Ah2, unsigned short* __restrict__ Al2)
{
    int n = (int)((blockIdx.x * 256 + threadIdx.x) >> 6);
    int lane = threadIdx.x & 63;
    if (n >= NN) return;
    int begin = (n == 0) ? 0 : rs[n - 1];
    int end = rs[n];
    int c = lane >> 1, h = lane & 1;             // true chunk c, 8B-half h
    int cc = c & 7;
    int sub = (c >> 3) * 64 + h * 4;
    float a0 = 0.f, a1 = 0.f, a2 = 0.f, a3 = 0.f;
    int j = begin;
    for (; j + 4 <= end; j += 4) {
        int s0 = csr_src[j], s1 = csr_src[j + 1], s2 = csr_src[j + 2], s3 = csr_src[j + 3];
        ushort4 v0 = *(const ushort4*)&t1s[(size_t)s0 * 256 + sub + ((cc ^ (s0 & 7)) * 8)];
        ushort4 v1 = *(const ushort4*)&t1s[(size_t)s1 * 256 + sub + ((cc ^ (s1 & 7)) * 8)];
        ushort4 v2 = *(const ushort4*)&t1s[(size_t)s2 * 256 + sub + ((cc ^ (s2 & 7)) * 8)];
        ushort4 v3 = *(const ushort4*)&t1s[(size_t)s3 * 256 + sub + ((cc ^ (s3 & 7)) * 8)];
        a0 += bf2f(v0.x); a1 += bf2f(v0.y); a2 += bf2f(v0.z); a3 += bf2f(v0.w);
        a0 += bf2f(v1.x); a1 += bf2f(v1.y); a2 += bf2f(v1.z); a3 += bf2f(v1.w);
        a0 += bf2f(v2.x); a1 += bf2f(v2.y); a2 += bf2f(v2.z); a3 += bf2f(v2.w);
        a0 += bf2f(v3.x); a1 += bf2f(v3.y); a2 += bf2f(v3.z); a3 += bf2f(v3.w);
    }
    for (; j < end; ++j) {
        int s = csr_src[j];
        ushort4 v = *(const ushort4*)&t1s[(size_t)s * 256 + sub + ((cc ^ (s & 7)) * 8)];
        a0 += bf2f(v.x); a1 += bf2f(v.y); a2 += bf2f(v.z); a3 += bf2f(v.w);
    }
    float win = inv_in[n];
    int k0 = c * 8 + h * 4;
    float4 bb = *(const float4*)&b1[k0];
    float x0 = fmaxf(fmaf(a0, win, bb.x), 0.f);
    float x1 = fmaxf(fmaf(a1, win, bb.y), 0.f);
    float x2 = fmaxf(fmaf(a2, win, bb.z), 0.f);
    float x3 = fmaxf(fmaf(a3, win, bb.w), 0.f);
    unsigned short h0 = f2bf(x0), h1 = f2bf(x1), h2 = f2bf(x2), h3 = f2bf(x3);
    ushort4 hv = {h0, h1, h2, h3};
    ushort4 lv = {f2bf(x0 - bf2f(h0)), f2bf(x1 - bf2f(h1)),
                  f2bf(x2 - bf2f(h2)), f2bf(x3 - bf2f(h3))};
    size_t off = (size_t)n * 256 + sub + ((cc ^ (n & 7)) * 8);
    *(ushort4*)&Ah2[off] = hv;
    *(ushort4*)&Al2[off] = lv;
}

// ---------- gather 64-wide: pure sum, unroll-4 pipeline, + inv_in scale + b2 ----------
__global__ __launch_bounds__(256) void gather64_kernel(const unsigned short* __restrict__ t2,
    const int* __restrict__ csr_src, const int* __restrict__ rs,
    const float* __restrict__ inv_in, const float* __restrict__ b2,
    float* __restrict__ out)
{
    int n = (int)((blockIdx.x * 256 + threadIdx.x) >> 6);
    int lane = threadIdx.x & 63;
    if (n >= NN) return;
    int begin = (n == 0) ? 0 : rs[n - 1];
    int end = rs[n];
    float acc = 0.f;
    int j = begin;
    for (; j + 4 <= end; j += 4) {
        int s0 = csr_src[j], s1 = csr_src[j + 1], s2 = csr_src[j + 2], s3 = csr_src[j + 3];
        float v0 = bf2f(t2[(size_t)s0 * 64 + lane]);
        float v1 = bf2f(t2[(size_t)s1 * 64 + lane]);
        float v2 = bf2f(t2[(size_t)s2 * 64 + lane]);
        float v3 = bf2f(t2[(size_t)s3 * 64 + lane]);
        acc += v0; acc += v1; acc += v2; acc += v3;
    }
    for (; j < end; ++j) {
        int s = csr_src[j];
        acc += bf2f(t2[(size_t)s * 64 + lane]);
    }
    out[(size_t)n * 64 + lane] = fmaf(acc, inv_in[n], b2[lane]);
}

extern "C" void kernel_launch(void* const* d_in, const int* in_sizes, int n_in,
                              void* d_out, int out_size, void* d_ws, size_t ws_size,
                              hipStream_t stream)
{
    const float* features = (const float*)d_in[0];
    const int*   edge_index = (const int*)d_in[1];
    const float* W1 = (const float*)d_in[2];
    const float* b1 = (const float*)d_in[3];
    const float* W2 = (const float*)d_in[4];
    const float* b2 = (const float*)d_in[5];
    float* out = (float*)d_out;
    const int* src = edge_index;
    const int* dst = edge_index + NE;

    char* p = (char*)d_ws;
    int* cnt_out = (int*)p;            p += (size_t)NN * 4;
    int* cnt_in  = (int*)p;            p += (size_t)NN * 4;
    float* inv_out = (float*)p;        p += (size_t)NN * 4;
    float* inv_in  = (float*)p;        p += (size_t)NN * 4;
    int* rs      = (int*)p;            p += (size_t)NN * 4;
    int* csr_src = (int*)p;            p += (size_t)NE * 4;
    int* bsum    = (int*)p;            p += 64 * 4;
    int* bexcl   = (int*)p;            p += 64 * 4;
    unsigned short* W1T = (unsigned short*)p;  p += (size_t)256 * 512 * 2;
    unsigned short* W2T = (unsigned short*)p;  p += (size_t)64 * 512 * 2;
    unsigned short* Xh  = (unsigned short*)p;  p += (size_t)MPAD * 256 * 2;
    unsigned short* Xl  = (unsigned short*)p;  p += (size_t)MPAD * 256 * 2;
    unsigned short* t1s = (unsigned short*)p;  p += (size_t)NN * 256 * 2;
    unsigned short* Ah2 = (unsigned short*)p;  p += (size_t)MPAD * 256 * 2;
    unsigned short* Al2 = (unsigned short*)p;  p += (size_t)MPAD * 256 * 2;
    unsigned short* t2  = (unsigned short*)p;  p += (size_t)NN * 64 * 2;

    hipMemsetAsync(cnt_out, 0, 2 * (size_t)NN * sizeof(int), stream);

    count_kernel<<<(NE + 255) / 256, 256, 0, stream>>>(src, dst, cnt_out, cnt_in, NE);
    inv_kernel<<<(NN + 255) / 256, 256, 0, stream>>>(cnt_out, cnt_in, inv_out, inv_in, NN);
    scanA_kernel<<<SCAN_BLOCKS, 256, 0, stream>>>(cnt_in, bsum);
    scanB_kernel<<<1, 64, 0, stream>>>(bsum, bexcl);
    scanC_kernel<<<SCAN_BLOCKS, 256, 0, stream>>>(cnt_in, bexcl, rs);
    fill_kernel<<<(NE + 255) / 256, 256, 0, stream>>>(src, dst, rs, csr_src, NE);

    splitX_kernel<<<(NN * 32 + 255) / 256, 256, 0, stream>>>(features, Xh, Xl);
    splitW_kernel<<<(256 * 32 + 255) / 256, 256, 0, stream>>>(W1, W1T, 256);
    splitW_kernel<<<(64 * 32 + 255) / 256, 256, 0, stream>>>(W2, W2T, 64);

    // t1s(bf16, swz) = (X @ W1) * inv_out[row]
    gemm_sp_kernel<128, true><<<dim3(MPAD / 128, 2), 256, 0, stream>>>(
        Xh, Xl, W1T, inv_out, t1s, NN, 256);

    // Ah2/Al2 = split(relu(sum_{e:dst=n} t1s[src] * inv_in[n] + b1))
    gather256_kernel<<<(NN * 64 + 255) / 256, 256, 0, stream>>>(
        t1s, csr_src, rs, inv_in, b1, Ah2, Al2);

    // t2(bf16, linear) = (h2 @ W2) * inv_out[row]
    gemm_sp_kernel<64, false><<<dim3(MPAD / 128, 1), 256, 0, stream>>>(
        Ah2, Al2, W2T, inv_out, t2, NN, 64);

    // out = sum t2[src] * inv_in[n] + b2
    gather64_kernel<<<(NN * 64 + 255) / 256, 256, 0, stream>>>(
        t2, csr_src, rs, inv_in, b2, out);
}